// Round 1
// baseline (309.825 us; speedup 1.0000x reference)
//
#include <hip/hip_runtime.h>

typedef short v8s __attribute__((ext_vector_type(8)));
typedef short v4s __attribute__((ext_vector_type(4)));
typedef float v4f __attribute__((ext_vector_type(4)));

constexpr int Bb = 2, S = 2048, D = 1024, H = 16;
constexpr int M = Bb * S;   // 4096

#define DEV __device__ __forceinline__

DEV short f2bf(float f){
  unsigned u = __builtin_bit_cast(unsigned, f);
  u = (u + 0x7FFF + ((u >> 16) & 1)) >> 16;
  return (short)u;
}

#define GLDS(gp, lp) __builtin_amdgcn_global_load_lds( \
    (const __attribute__((address_space(1))) void*)(gp), \
    (__attribute__((address_space(3))) void*)(lp), 16, 0, 0)

// ---------------- prep: xb = bf16(x); xtb = bf16(x + tg*Wt + bt) ----------------
__global__ void prep_kernel(const float* __restrict__ x, const float* __restrict__ tg,
                            const float* __restrict__ Wt, const float* __restrict__ bt,
                            short* __restrict__ xb, short* __restrict__ xtb){
  int i = blockIdx.x * blockDim.x + threadIdx.x;     // one float4 (4 elems)
  int row = i >> 8;                                   // 256 float4 per 1024-row
  int c4  = i & 255;
  float4 xv = reinterpret_cast<const float4*>(x)[i];
  float4 wv = reinterpret_cast<const float4*>(Wt)[c4];
  float4 bv = reinterpret_cast<const float4*>(bt)[c4];
  float g = tg[row];
  float xs[4] = {xv.x, xv.y, xv.z, xv.w};
  float ws[4] = {wv.x, wv.y, wv.z, wv.w};
  float bs[4] = {bv.x, bv.y, bv.z, bv.w};
  v4s a, b;
  #pragma unroll
  for (int e = 0; e < 4; ++e){
    a[e] = f2bf(xs[e]);
    b[e] = f2bf(xs[e] + g * ws[e] + bs[e]);
  }
  *reinterpret_cast<v4s*>(&xb[(size_t)i * 4])  = a;
  *reinterpret_cast<v4s*>(&xtb[(size_t)i * 4]) = b;
}

// ---------------- weight fp32 -> bf16 ----------------
__global__ void wconv_kernel(const float* __restrict__ src, short* __restrict__ dst){
  int i = blockIdx.x * blockDim.x + threadIdx.x;
  float4 v = reinterpret_cast<const float4*>(src)[i];
  v4s o; o[0] = f2bf(v.x); o[1] = f2bf(v.y); o[2] = f2bf(v.z); o[3] = f2bf(v.w);
  *reinterpret_cast<v4s*>(&dst[(size_t)i * 4]) = o;
}

// ---------------- GEMM: C[m,n] = (sum_k A[m,k]*Bw[n,k] + bias[n]) * alpha ----------------
// A: [M,1024] bf16 row-major. Bw: [1024,1024] bf16, row n holds k contiguous (B^T layout).
// 128x128 tile, BK=32, 4 waves (2x2), each wave 64x64 = 4x4 frags of 16x16x32.
template<bool F32OUT>
__global__ __launch_bounds__(256, 2)
void gemm_bt(const short* __restrict__ A, const short* __restrict__ Bw,
             const float* __restrict__ bias, float alpha, void* __restrict__ Cout){
  __shared__ short As[128 * 32];
  __shared__ short Bs[128 * 32];
  const int t = threadIdx.x;
  const int w = t >> 6, l = t & 63;
  const int m0 = blockIdx.x * 128;
  const int n0 = blockIdx.y * 128;
  const int wm = (w >> 1) * 64, wn = (w & 1) * 64;

  v4f acc[4][4] = {};

  const int srow = w * 16 + (l >> 2);   // staging row (j adds 64)
  const int scol = (l & 3) * 8;         // staging col element offset

  for (int k0 = 0; k0 < D; k0 += 32){
    #pragma unroll
    for (int j = 0; j < 2; ++j){
      GLDS(A  + (size_t)(m0 + j * 64 + srow) * D + k0 + scol, As + j * 2048 + w * 512 + l * 8);
      GLDS(Bw + (size_t)(n0 + j * 64 + srow) * D + k0 + scol, Bs + j * 2048 + w * 512 + l * 8);
    }
    __syncthreads();
    v8s af[4], bfr[4];
    #pragma unroll
    for (int mi = 0; mi < 4; ++mi)
      af[mi] = *reinterpret_cast<const v8s*>(&As[(wm + mi * 16 + (l & 15)) * 32 + (l >> 4) * 8]);
    #pragma unroll
    for (int ni = 0; ni < 4; ++ni)
      bfr[ni] = *reinterpret_cast<const v8s*>(&Bs[(wn + ni * 16 + (l & 15)) * 32 + (l >> 4) * 8]);
    #pragma unroll
    for (int mi = 0; mi < 4; ++mi)
      #pragma unroll
      for (int ni = 0; ni < 4; ++ni)
        acc[mi][ni] = __builtin_amdgcn_mfma_f32_16x16x32_bf16(af[mi], bfr[ni], acc[mi][ni], 0, 0, 0);
    __syncthreads();
  }

  #pragma unroll
  for (int mi = 0; mi < 4; ++mi){
    const int row = m0 + wm + mi * 16 + (l >> 4) * 4;
    #pragma unroll
    for (int ni = 0; ni < 4; ++ni){
      const int col = n0 + wn + ni * 16 + (l & 15);
      const float bcol = bias[col];
      #pragma unroll
      for (int r = 0; r < 4; ++r){
        float val = (acc[mi][ni][r] + bcol) * alpha;
        if (F32OUT) reinterpret_cast<float*>(Cout)[(size_t)(row + r) * D + col] = val;
        else        reinterpret_cast<short*>(Cout)[(size_t)(row + r) * D + col] = f2bf(val);
      }
    }
  }
}

// ---------------- causal flash attention ----------------
// grid: (S/64, B*H). 4 waves, each owns 16 q-rows. KV tiles of 64.
// Q pre-scaled by 1/sqrt(64) in its projection epilogue.
__global__ __launch_bounds__(256, 2)
void attn_kernel(const short* __restrict__ Q, const short* __restrict__ K,
                 const short* __restrict__ V, const int* __restrict__ maskp,
                 short* __restrict__ O){
  __shared__ short Ks[64 * 64];       // [kv][d]
  __shared__ short Vt[64 * 64];       // [d][kv] (transposed)
  __shared__ short Ps[4][16 * 64];    // per-wave P tile [q][kv]
  const int t = threadIdx.x, w = t >> 6, l = t & 63;
  const int bh = blockIdx.y, b = bh >> 4, h = bh & 15;
  const int q0 = blockIdx.x * 64;

  v8s qf[2];
  #pragma unroll
  for (int kc = 0; kc < 2; ++kc)
    qf[kc] = *reinterpret_cast<const v8s*>(
        &Q[(size_t)(b * S + q0 + w * 16 + (l & 15)) * D + h * 64 + kc * 32 + (l >> 4) * 8]);

  v4f accO[4] = {};
  float mrow[4] = {-1e30f, -1e30f, -1e30f, -1e30f};
  float lrow[4] = {0.f, 0.f, 0.f, 0.f};

  for (int kt = 0; kt <= blockIdx.x; ++kt){
    const int kv0 = kt * 64;
    // stage K [64][64] via global_load_lds
    #pragma unroll
    for (int j = 0; j < 2; ++j){
      int krow = j * 32 + w * 8 + (l >> 3);
      GLDS(K + (size_t)(b * S + kv0 + krow) * D + h * 64 + (l & 7) * 8,
           Ks + j * 2048 + w * 512 + l * 8);
    }
    // stage V transposed: coalesced 16B reads, scalar LDS writes
    #pragma unroll
    for (int j = 0; j < 2; ++j){
      int kvr = j * 32 + (t >> 3);
      int d0  = (t & 7) * 8;
      v8s vv = *reinterpret_cast<const v8s*>(&V[(size_t)(b * S + kv0 + kvr) * D + h * 64 + d0]);
      #pragma unroll
      for (int e = 0; e < 8; ++e) Vt[(d0 + e) * 64 + kvr] = vv[e];
    }
    __syncthreads();

    // scores: 16 q-rows x 64 kv
    v4f sc[4] = {};
    #pragma unroll
    for (int nt = 0; nt < 4; ++nt)
      #pragma unroll
      for (int kc = 0; kc < 2; ++kc){
        v8s kf = *reinterpret_cast<const v8s*>(&Ks[(nt * 16 + (l & 15)) * 64 + kc * 32 + (l >> 4) * 8]);
        sc[nt] = __builtin_amdgcn_mfma_f32_16x16x32_bf16(qf[kc], kf, sc[nt], 0, 0, 0);
      }

    // causal + padding mask
    const int qbase = q0 + w * 16 + (l >> 4) * 4;
    #pragma unroll
    for (int nt = 0; nt < 4; ++nt){
      const int kvg = kv0 + nt * 16 + (l & 15);
      const bool pm = (maskp[b * S + kvg] != 0);
      #pragma unroll
      for (int r = 0; r < 4; ++r)
        if (!pm || kvg > qbase + r) sc[nt][r] = -1e30f;
    }

    // online softmax (rows live across 16-lane groups)
    #pragma unroll
    for (int r = 0; r < 4; ++r){
      float tmax = fmaxf(fmaxf(sc[0][r], sc[1][r]), fmaxf(sc[2][r], sc[3][r]));
      tmax = fmaxf(tmax, __shfl_xor(tmax, 1));
      tmax = fmaxf(tmax, __shfl_xor(tmax, 2));
      tmax = fmaxf(tmax, __shfl_xor(tmax, 4));
      tmax = fmaxf(tmax, __shfl_xor(tmax, 8));
      const float mnew = fmaxf(mrow[r], tmax);
      const float resc = __expf(mrow[r] - mnew);
      float psum = 0.f;
      #pragma unroll
      for (int nt = 0; nt < 4; ++nt){
        float p = __expf(sc[nt][r] - mnew);
        sc[nt][r] = p;
        psum += p;
      }
      psum += __shfl_xor(psum, 1);
      psum += __shfl_xor(psum, 2);
      psum += __shfl_xor(psum, 4);
      psum += __shfl_xor(psum, 8);
      lrow[r] = lrow[r] * resc + psum;
      mrow[r] = mnew;
      #pragma unroll
      for (int dt = 0; dt < 4; ++dt) accO[dt][r] *= resc;
    }

    // P -> LDS (C-layout) -> A-fragment layout
    #pragma unroll
    for (int nt = 0; nt < 4; ++nt)
      #pragma unroll
      for (int r = 0; r < 4; ++r)
        Ps[w][((l >> 4) * 4 + r) * 64 + nt * 16 + (l & 15)] = f2bf(sc[nt][r]);

    // PV: out[16 q][64 d] += P[16][64] * V[64][64]
    #pragma unroll
    for (int kc = 0; kc < 2; ++kc){
      v8s pf = *reinterpret_cast<const v8s*>(&Ps[w][(l & 15) * 64 + kc * 32 + (l >> 4) * 8]);
      #pragma unroll
      for (int dt = 0; dt < 4; ++dt){
        v8s vf = *reinterpret_cast<const v8s*>(&Vt[(dt * 16 + (l & 15)) * 64 + kc * 32 + (l >> 4) * 8]);
        accO[dt] = __builtin_amdgcn_mfma_f32_16x16x32_bf16(pf, vf, accO[dt], 0, 0, 0);
      }
    }
    __syncthreads();
  }

  // epilogue: O[b, q, h*64+d] = accO / l
  #pragma unroll
  for (int dt = 0; dt < 4; ++dt){
    const int col = h * 64 + dt * 16 + (l & 15);
    #pragma unroll
    for (int r = 0; r < 4; ++r){
      const int row = q0 + w * 16 + (l >> 4) * 4 + r;
      O[(size_t)(b * S + row) * D + col] = f2bf(accO[dt][r] / lrow[r]);
    }
  }
}

extern "C" void kernel_launch(void* const* d_in, const int* in_sizes, int n_in,
                              void* d_out, int out_size, void* d_ws, size_t ws_size,
                              hipStream_t stream){
  const float* x   = (const float*)d_in[0];
  const float* tg  = (const float*)d_in[1];
  const int*   msk = (const int*)d_in[2];
  const float* Wq  = (const float*)d_in[3];
  const float* bq  = (const float*)d_in[4];
  const float* Wk  = (const float*)d_in[5];
  const float* bk  = (const float*)d_in[6];
  const float* Wv  = (const float*)d_in[7];
  const float* bv  = (const float*)d_in[8];
  const float* Wo  = (const float*)d_in[9];
  const float* bo  = (const float*)d_in[10];
  const float* Wt  = (const float*)d_in[11];
  const float* bt  = (const float*)d_in[12];

  char* ws = (char*)d_ws;
  const size_t MB = 1u << 20;
  short* xb  = (short*)(ws);             // 8 MB
  short* xtb = (short*)(ws + 8 * MB);    // 8 MB
  short* Wqb = (short*)(ws + 16 * MB);   // 2 MB
  short* Wkb = (short*)(ws + 18 * MB);
  short* Wvb = (short*)(ws + 20 * MB);
  short* Wob = (short*)(ws + 22 * MB);
  short* Qb  = (short*)(ws + 24 * MB);   // 8 MB
  short* Kb  = (short*)(ws + 32 * MB);
  short* Vb  = (short*)(ws + 40 * MB);
  short* Ab  = (short*)(ws + 48 * MB);   // 8 MB -> 56 MB total

  prep_kernel<<<4096, 256, 0, stream>>>(x, tg, Wt, bt, xb, xtb);
  wconv_kernel<<<1024, 256, 0, stream>>>(Wq, Wqb);
  wconv_kernel<<<1024, 256, 0, stream>>>(Wk, Wkb);
  wconv_kernel<<<1024, 256, 0, stream>>>(Wv, Wvb);
  wconv_kernel<<<1024, 256, 0, stream>>>(Wo, Wob);

  dim3 ggrid(M / 128, D / 128);
  gemm_bt<false><<<ggrid, 256, 0, stream>>>(xtb, Wqb, bq, 0.125f, Qb);  // Q pre-scaled
  gemm_bt<false><<<ggrid, 256, 0, stream>>>(xtb, Wkb, bk, 1.0f, Kb);
  gemm_bt<false><<<ggrid, 256, 0, stream>>>(xb,  Wvb, bv, 1.0f, Vb);

  attn_kernel<<<dim3(S / 64, Bb * H), 256, 0, stream>>>(Qb, Kb, Vb, msk, Ab);

  gemm_bt<true><<<ggrid, 256, 0, stream>>>(Ab, Wob, bo, 1.0f, d_out);
}

// Round 2
// 192.720 us; speedup vs baseline: 1.6076x; 1.6076x over previous
//
#include <hip/hip_runtime.h>

typedef short v8s __attribute__((ext_vector_type(8)));
typedef short v4s __attribute__((ext_vector_type(4)));
typedef float v4f __attribute__((ext_vector_type(4)));

constexpr int Bb = 2, S = 2048, D = 1024, H = 16;
constexpr int M = Bb * S;   // 4096

#define DEV __device__ __forceinline__

DEV short f2bf(float f){
  unsigned u = __builtin_bit_cast(unsigned, f);
  u = (u + 0x7FFF + ((u >> 16) & 1)) >> 16;
  return (short)u;
}

#define GLDS(gp, lp) __builtin_amdgcn_global_load_lds( \
    (const __attribute__((address_space(1))) void*)(gp), \
    (__attribute__((address_space(3))) void*)(lp), 16, 0, 0)

// ---------------- prep: xb = bf16(x); xtb = bf16(x + tg*Wt + bt) ----------------
__global__ void prep_kernel(const float* __restrict__ x, const float* __restrict__ tg,
                            const float* __restrict__ Wt, const float* __restrict__ bt,
                            short* __restrict__ xb, short* __restrict__ xtb){
  int i = blockIdx.x * blockDim.x + threadIdx.x;     // one float4 (4 elems)
  int row = i >> 8;
  int c4  = i & 255;
  float4 xv = reinterpret_cast<const float4*>(x)[i];
  float4 wv = reinterpret_cast<const float4*>(Wt)[c4];
  float4 bv = reinterpret_cast<const float4*>(bt)[c4];
  float g = tg[row];
  float xs[4] = {xv.x, xv.y, xv.z, xv.w};
  float ws[4] = {wv.x, wv.y, wv.z, wv.w};
  float bs[4] = {bv.x, bv.y, bv.z, bv.w};
  v4s a, b;
  #pragma unroll
  for (int e = 0; e < 4; ++e){
    a[e] = f2bf(xs[e]);
    b[e] = f2bf(xs[e] + g * ws[e] + bs[e]);
  }
  *reinterpret_cast<v4s*>(&xb[(size_t)i * 4])  = a;
  *reinterpret_cast<v4s*>(&xtb[(size_t)i * 4]) = b;
}

// ---------------- weight fp32 -> bf16 (4 weights in one launch) ----------------
struct WPtrs { const float* s[4]; short* d[4]; };
__global__ void wconv4_kernel(WPtrs p){
  int which = blockIdx.y;
  int i = blockIdx.x * blockDim.x + threadIdx.x;
  float4 v = reinterpret_cast<const float4*>(p.s[which])[i];
  v4s o; o[0] = f2bf(v.x); o[1] = f2bf(v.y); o[2] = f2bf(v.z); o[3] = f2bf(v.w);
  *reinterpret_cast<v4s*>(&p.d[which][(size_t)i * 4]) = o;
}

// ---------------- GEMM: C[m,n] = (sum_k A[m,k]*Bw[n,k] + bias) * alpha ----------------
// A rows: output-row index; Bw rows: output-col index; both K=1024 contiguous.
// BIAS_ROW=false: bias[col] (standard). BIAS_ROW=true: bias[row] (V^T production).
template<bool F32OUT, bool BIAS_ROW>
__global__ __launch_bounds__(256, 2)
void gemm_bt(const short* __restrict__ A, const short* __restrict__ Bw,
             const float* __restrict__ bias, float alpha, void* __restrict__ Cout,
             int ldc){
  __shared__ short As[128 * 32];
  __shared__ short Bs[128 * 32];
  const int t = threadIdx.x;
  const int w = t >> 6, l = t & 63;
  const int m0 = blockIdx.x * 128;
  const int n0 = blockIdx.y * 128;
  const int wm = (w >> 1) * 64, wn = (w & 1) * 64;

  v4f acc[4][4] = {};

  const int srow = w * 16 + (l >> 2);
  const int scol = (l & 3) * 8;

  for (int k0 = 0; k0 < D; k0 += 32){
    #pragma unroll
    for (int j = 0; j < 2; ++j){
      GLDS(A  + (size_t)(m0 + j * 64 + srow) * D + k0 + scol, As + j * 2048 + w * 512 + l * 8);
      GLDS(Bw + (size_t)(n0 + j * 64 + srow) * D + k0 + scol, Bs + j * 2048 + w * 512 + l * 8);
    }
    __syncthreads();
    v8s af[4], bfr[4];
    #pragma unroll
    for (int mi = 0; mi < 4; ++mi)
      af[mi] = *reinterpret_cast<const v8s*>(&As[(wm + mi * 16 + (l & 15)) * 32 + (l >> 4) * 8]);
    #pragma unroll
    for (int ni = 0; ni < 4; ++ni)
      bfr[ni] = *reinterpret_cast<const v8s*>(&Bs[(wn + ni * 16 + (l & 15)) * 32 + (l >> 4) * 8]);
    #pragma unroll
    for (int mi = 0; mi < 4; ++mi)
      #pragma unroll
      for (int ni = 0; ni < 4; ++ni)
        acc[mi][ni] = __builtin_amdgcn_mfma_f32_16x16x32_bf16(af[mi], bfr[ni], acc[mi][ni], 0, 0, 0);
    __syncthreads();
  }

  #pragma unroll
  for (int mi = 0; mi < 4; ++mi){
    const int row = m0 + wm + mi * 16 + (l >> 4) * 4;
    #pragma unroll
    for (int ni = 0; ni < 4; ++ni){
      const int col = n0 + wn + ni * 16 + (l & 15);
      const float bcol = BIAS_ROW ? 0.f : bias[col];
      #pragma unroll
      for (int r = 0; r < 4; ++r){
        float bsel = BIAS_ROW ? bias[row + r] : bcol;
        float val = (acc[mi][ni][r] + bsel) * alpha;
        if (F32OUT) reinterpret_cast<float*>(Cout)[(size_t)(row + r) * ldc + col] = val;
        else        reinterpret_cast<short*>(Cout)[(size_t)(row + r) * ldc + col] = f2bf(val);
      }
    }
  }
}

// ---------------- causal flash attention ----------------
// grid: (S/128, B*H). 4 waves x 32 q-rows = 128 q-rows per block. KV tiles of 64.
// K: bf16 [M][1024] (rows=seq). VT: bf16 [1024][M] (rows=feature -> V^T rows).
// All LDS tiles use chunk-XOR swizzle: 16B chunk c of row r stored at chunk c^(r&7).
__global__ __launch_bounds__(256, 2)
void attn_kernel(const short* __restrict__ Q, const short* __restrict__ K,
                 const short* __restrict__ VT, const int* __restrict__ maskp,
                 short* __restrict__ O){
  __shared__ short Ks[64 * 64];
  __shared__ short Vs[64 * 64];        // V^T tile: rows = d, cols = kv
  __shared__ short Ps[4][32 * 64];     // per-wave P [q_local][kv], swizzled
  const int t = threadIdx.x, w = t >> 6, l = t & 63;
  const int bh = blockIdx.y, b = bh >> 4, h = bh & 15;
  // complementary work pairing: blocks bi and bi+256 get qx and 15-qx
  const int qx = (blockIdx.y & 16) ? ((int)gridDim.x - 1 - (int)blockIdx.x) : (int)blockIdx.x;
  const int q0 = qx * 128;
  const int qw = q0 + w * 32;

  v8s qf[2][2];
  #pragma unroll
  for (int mi = 0; mi < 2; ++mi)
    #pragma unroll
    for (int kc = 0; kc < 2; ++kc)
      qf[mi][kc] = *reinterpret_cast<const v8s*>(
          &Q[(size_t)(b * S + qw + mi * 16 + (l & 15)) * D + h * 64 + kc * 32 + (l >> 4) * 8]);

  v4f accO[2][4] = {};
  float mrow[2][4], lrow[2][4];
  #pragma unroll
  for (int mi = 0; mi < 2; ++mi)
    #pragma unroll
    for (int r = 0; r < 4; ++r){ mrow[mi][r] = -1e30f; lrow[mi][r] = 0.f; }

  const int nkt = 2 * qx + 2;
  for (int kt = 0; kt < nkt; ++kt){
    const int kv0 = kt * 64;
    // stage K and V^T tiles, pre-swizzled global source -> linear LDS dest
    #pragma unroll
    for (int j = 0; j < 2; ++j){
      const int cix = j * 256 + t;
      const int row = cix >> 3;
      const int c   = (cix & 7) ^ (row & 7);
      GLDS(K  + (size_t)(b * S + kv0 + row) * D + h * 64 + c * 8, Ks + cix * 8);
      GLDS(VT + (size_t)(h * 64 + row) * M + b * S + kv0 + c * 8, Vs + cix * 8);
    }
    __syncthreads();

    // QK^T: sc[mi][nt] = Q[32q] x K^T -> 32q x 64kv
    v4f sc[2][4] = {};
    #pragma unroll
    for (int nt = 0; nt < 4; ++nt){
      const int R = nt * 16 + (l & 15);
      #pragma unroll
      for (int kc = 0; kc < 2; ++kc){
        v8s kf = *reinterpret_cast<const v8s*>(&Ks[R * 64 + (((kc * 4 + (l >> 4)) ^ (R & 7)) * 8)]);
        sc[0][nt] = __builtin_amdgcn_mfma_f32_16x16x32_bf16(qf[0][kc], kf, sc[0][nt], 0, 0, 0);
        sc[1][nt] = __builtin_amdgcn_mfma_f32_16x16x32_bf16(qf[1][kc], kf, sc[1][nt], 0, 0, 0);
      }
    }

    // causal + padding mask
    #pragma unroll
    for (int nt = 0; nt < 4; ++nt){
      const int kvg = kv0 + nt * 16 + (l & 15);
      const bool ok = (maskp[b * S + kvg] != 0);
      #pragma unroll
      for (int mi = 0; mi < 2; ++mi){
        const int qb = qw + mi * 16 + (l >> 4) * 4;
        #pragma unroll
        for (int r = 0; r < 4; ++r)
          if (!ok || kvg > qb + r) sc[mi][nt][r] = -1e30f;
      }
    }

    // online softmax (rows live across 16-lane groups)
    #pragma unroll
    for (int mi = 0; mi < 2; ++mi)
      #pragma unroll
      for (int r = 0; r < 4; ++r){
        float tmax = fmaxf(fmaxf(sc[mi][0][r], sc[mi][1][r]), fmaxf(sc[mi][2][r], sc[mi][3][r]));
        tmax = fmaxf(tmax, __shfl_xor(tmax, 1));
        tmax = fmaxf(tmax, __shfl_xor(tmax, 2));
        tmax = fmaxf(tmax, __shfl_xor(tmax, 4));
        tmax = fmaxf(tmax, __shfl_xor(tmax, 8));
        const float mnew = fmaxf(mrow[mi][r], tmax);
        const float resc = __expf(mrow[mi][r] - mnew);
        float psum = 0.f;
        #pragma unroll
        for (int nt = 0; nt < 4; ++nt){
          float p = __expf(sc[mi][nt][r] - mnew);
          sc[mi][nt][r] = p;
          psum += p;
        }
        psum += __shfl_xor(psum, 1);
        psum += __shfl_xor(psum, 2);
        psum += __shfl_xor(psum, 4);
        psum += __shfl_xor(psum, 8);
        lrow[mi][r] = lrow[mi][r] * resc + psum;
        mrow[mi][r] = mnew;
        #pragma unroll
        for (int dt = 0; dt < 4; ++dt) accO[mi][dt][r] *= resc;
      }

    // P -> LDS (swizzled) in A-fragment-readable layout
    #pragma unroll
    for (int mi = 0; mi < 2; ++mi)
      #pragma unroll
      for (int nt = 0; nt < 4; ++nt)
        #pragma unroll
        for (int r = 0; r < 4; ++r){
          const int ql = mi * 16 + (l >> 4) * 4 + r;
          const int kc8 = nt * 2 + ((l & 15) >> 3);     // kv>>3
          Ps[w][ql * 64 + ((kc8 ^ (ql & 7)) * 8) + (l & 7)] = f2bf(sc[mi][nt][r]);
        }

    // PV: accO[32q][64d] += P[32][64] x V[64][64]  (Vs rows = V^T rows = d)
    #pragma unroll
    for (int kc = 0; kc < 2; ++kc){
      v8s pf[2];
      #pragma unroll
      for (int mi = 0; mi < 2; ++mi){
        const int qq = mi * 16 + (l & 15);
        pf[mi] = *reinterpret_cast<const v8s*>(&Ps[w][qq * 64 + (((kc * 4 + (l >> 4)) ^ (qq & 7)) * 8)]);
      }
      #pragma unroll
      for (int dt = 0; dt < 4; ++dt){
        const int dr = dt * 16 + (l & 15);
        v8s vf = *reinterpret_cast<const v8s*>(&Vs[dr * 64 + (((kc * 4 + (l >> 4)) ^ (dr & 7)) * 8)]);
        accO[0][dt] = __builtin_amdgcn_mfma_f32_16x16x32_bf16(pf[0], vf, accO[0][dt], 0, 0, 0);
        accO[1][dt] = __builtin_amdgcn_mfma_f32_16x16x32_bf16(pf[1], vf, accO[1][dt], 0, 0, 0);
      }
    }
    __syncthreads();
  }

  // epilogue
  #pragma unroll
  for (int mi = 0; mi < 2; ++mi)
    #pragma unroll
    for (int dt = 0; dt < 4; ++dt){
      const int col = h * 64 + dt * 16 + (l & 15);
      #pragma unroll
      for (int r = 0; r < 4; ++r){
        const int row = qw + mi * 16 + (l >> 4) * 4 + r;
        O[(size_t)(b * S + row) * D + col] = f2bf(accO[mi][dt][r] / lrow[mi][r]);
      }
    }
}

extern "C" void kernel_launch(void* const* d_in, const int* in_sizes, int n_in,
                              void* d_out, int out_size, void* d_ws, size_t ws_size,
                              hipStream_t stream){
  const float* x   = (const float*)d_in[0];
  const float* tg  = (const float*)d_in[1];
  const int*   msk = (const int*)d_in[2];
  const float* Wq  = (const float*)d_in[3];
  const float* bq  = (const float*)d_in[4];
  const float* Wk  = (const float*)d_in[5];
  const float* bk  = (const float*)d_in[6];
  const float* Wv  = (const float*)d_in[7];
  const float* bv  = (const float*)d_in[8];
  const float* Wo  = (const float*)d_in[9];
  const float* bo  = (const float*)d_in[10];
  const float* Wt  = (const float*)d_in[11];
  const float* bt  = (const float*)d_in[12];

  char* ws = (char*)d_ws;
  const size_t MB = 1u << 20;
  short* xb  = (short*)(ws);             // 8 MB
  short* xtb = (short*)(ws + 8 * MB);    // 8 MB
  short* Wqb = (short*)(ws + 16 * MB);   // 2 MB each
  short* Wkb = (short*)(ws + 18 * MB);
  short* Wvb = (short*)(ws + 20 * MB);
  short* Wob = (short*)(ws + 22 * MB);
  short* Qb  = (short*)(ws + 24 * MB);   // 8 MB
  short* Kb  = (short*)(ws + 32 * MB);
  short* VTb = (short*)(ws + 40 * MB);   // V^T [1024][4096]
  short* Ab  = (short*)(ws + 48 * MB);   // 8 MB -> 56 MB total

  prep_kernel<<<4096, 256, 0, stream>>>(x, tg, Wt, bt, xb, xtb);
  WPtrs wp; wp.s[0] = Wq; wp.s[1] = Wk; wp.s[2] = Wv; wp.s[3] = Wo;
  wp.d[0] = Wqb; wp.d[1] = Wkb; wp.d[2] = Wvb; wp.d[3] = Wob;
  wconv4_kernel<<<dim3(1024, 4), 256, 0, stream>>>(wp);

  dim3 ggrid(M / 128, D / 128);
  gemm_bt<false, false><<<ggrid, 256, 0, stream>>>(xtb, Wqb, bq, 0.125f, Qb, D);
  gemm_bt<false, false><<<ggrid, 256, 0, stream>>>(xtb, Wkb, bk, 1.0f, Kb, D);
  // V^T: rows = feature n, cols = token m  (swapped operands, bias per row)
  gemm_bt<false, true><<<dim3(D / 128, M / 128), 256, 0, stream>>>(Wvb, xb, bv, 1.0f, VTb, M);

  attn_kernel<<<dim3(S / 128, Bb * H), 256, 0, stream>>>(Qb, Kb, VTb, msk, Ab);

  gemm_bt<true, false><<<ggrid, 256, 0, stream>>>(Ab, Wob, bo, 1.0f, d_out, D);
}

// Round 3
// 166.105 us; speedup vs baseline: 1.8652x; 1.1602x over previous
//
#include <hip/hip_runtime.h>

typedef short v8s __attribute__((ext_vector_type(8)));
typedef short v4s __attribute__((ext_vector_type(4)));
typedef float v4f __attribute__((ext_vector_type(4)));
typedef int   v4i __attribute__((ext_vector_type(4)));

constexpr int Bb = 2, S = 2048, D = 1024, H = 16;
constexpr int M = Bb * S;   // 4096

#define DEV __device__ __forceinline__

DEV short f2bf(float f){
  unsigned u = __builtin_bit_cast(unsigned, f);
  u = (u + 0x7FFF + ((u >> 16) & 1)) >> 16;
  return (short)u;
}

DEV int swz(int r){ return (r ^ (r >> 2)) & 7; }

DEV int cvtpk(float lo, float hi){
  int r;
  asm("v_cvt_pk_bf16_f32 %0, %1, %2" : "=v"(r) : "v"(lo), "v"(hi));
  return r;
}

#if __has_builtin(__builtin_amdgcn_exp2f)
#define EXP2 __builtin_amdgcn_exp2f
#else
#define EXP2 exp2f
#endif

#define GLDS(gp, lp) __builtin_amdgcn_global_load_lds( \
    (const __attribute__((address_space(1))) void*)(gp), \
    (__attribute__((address_space(3))) void*)(lp), 16, 0, 0)

// ---------------- prep: xb = bf16(x); xtb = bf16(x + tg*Wt + bt) ----------------
__global__ void prep_kernel(const float* __restrict__ x, const float* __restrict__ tg,
                            const float* __restrict__ Wt, const float* __restrict__ bt,
                            short* __restrict__ xb, short* __restrict__ xtb){
  int i = blockIdx.x * blockDim.x + threadIdx.x;
  int row = i >> 8;
  int c4  = i & 255;
  float4 xv = reinterpret_cast<const float4*>(x)[i];
  float4 wv = reinterpret_cast<const float4*>(Wt)[c4];
  float4 bv = reinterpret_cast<const float4*>(bt)[c4];
  float g = tg[row];
  float xs[4] = {xv.x, xv.y, xv.z, xv.w};
  float ws[4] = {wv.x, wv.y, wv.z, wv.w};
  float bs[4] = {bv.x, bv.y, bv.z, bv.w};
  v4s a, b;
  #pragma unroll
  for (int e = 0; e < 4; ++e){
    a[e] = f2bf(xs[e]);
    b[e] = f2bf(xs[e] + g * ws[e] + bs[e]);
  }
  *reinterpret_cast<v4s*>(&xb[(size_t)i * 4])  = a;
  *reinterpret_cast<v4s*>(&xtb[(size_t)i * 4]) = b;
}

// ---------------- weight fp32 -> bf16 (4 weights in one launch) ----------------
struct WPtrs { const float* s[4]; short* d[4]; };
__global__ void wconv4_kernel(WPtrs p){
  int which = blockIdx.y;
  int i = blockIdx.x * blockDim.x + threadIdx.x;
  float4 v = reinterpret_cast<const float4*>(p.s[which])[i];
  v4s o; o[0] = f2bf(v.x); o[1] = f2bf(v.y); o[2] = f2bf(v.z); o[3] = f2bf(v.w);
  *reinterpret_cast<v4s*>(&p.d[which][(size_t)i * 4]) = o;
}

// ---------------- GEMM: C[m,n] = (sum_k A[m,k]*Bw[n,k] + bias) * alpha ----------------
// BK=64, XOR-swizzled LDS, double-buffered staging, one barrier per K-step.
template<bool F32OUT, bool BIAS_ROW>
__global__ __launch_bounds__(256, 2)
void gemm_bt(const short* __restrict__ A, const short* __restrict__ Bw,
             const float* __restrict__ bias, float alpha, void* __restrict__ Cout,
             int ldc){
  __shared__ short As[2][128 * 64];
  __shared__ short Bs[2][128 * 64];
  const int t = threadIdx.x;
  const int w = t >> 6, l = t & 63;
  const int m0 = blockIdx.x * 128;
  const int n0 = blockIdx.y * 128;
  const int wm = (w >> 1) * 64, wn = (w & 1) * 64;

  v4f acc[4][4] = {};

  auto stage = [&](int kt, int buf){
    const int k0 = kt * 64;
    #pragma unroll
    for (int j = 0; j < 4; ++j){
      const int cix = j * 256 + t;
      const int row = cix >> 3;
      const int c   = (cix & 7) ^ swz(row);
      GLDS(A  + (size_t)(m0 + row) * D + k0 + c * 8, &As[buf][cix * 8]);
      GLDS(Bw + (size_t)(n0 + row) * D + k0 + c * 8, &Bs[buf][cix * 8]);
    }
  };

  stage(0, 0);
  for (int kt = 0; kt < 16; ++kt){
    const int cur = kt & 1;
    __syncthreads();
    if (kt < 15) stage(kt + 1, cur ^ 1);
    #pragma unroll
    for (int kk = 0; kk < 2; ++kk){
      v8s af[4], bfr[4];
      #pragma unroll
      for (int mi = 0; mi < 4; ++mi){
        const int R = wm + mi * 16 + (l & 15);
        af[mi] = *reinterpret_cast<const v8s*>(&As[cur][R * 64 + (((kk * 4 + (l >> 4)) ^ swz(R)) * 8)]);
      }
      #pragma unroll
      for (int ni = 0; ni < 4; ++ni){
        const int R = wn + ni * 16 + (l & 15);
        bfr[ni] = *reinterpret_cast<const v8s*>(&Bs[cur][R * 64 + (((kk * 4 + (l >> 4)) ^ swz(R)) * 8)]);
      }
      #pragma unroll
      for (int mi = 0; mi < 4; ++mi)
        #pragma unroll
        for (int ni = 0; ni < 4; ++ni)
          acc[mi][ni] = __builtin_amdgcn_mfma_f32_16x16x32_bf16(af[mi], bfr[ni], acc[mi][ni], 0, 0, 0);
    }
  }

  #pragma unroll
  for (int mi = 0; mi < 4; ++mi){
    const int row = m0 + wm + mi * 16 + (l >> 4) * 4;
    #pragma unroll
    for (int ni = 0; ni < 4; ++ni){
      const int col = n0 + wn + ni * 16 + (l & 15);
      const float bcol = BIAS_ROW ? 0.f : bias[col];
      #pragma unroll
      for (int r = 0; r < 4; ++r){
        float bsel = BIAS_ROW ? bias[row + r] : bcol;
        float val = (acc[mi][ni][r] + bsel) * alpha;
        if (F32OUT) reinterpret_cast<float*>(Cout)[(size_t)(row + r) * ldc + col] = val;
        else        reinterpret_cast<short*>(Cout)[(size_t)(row + r) * ldc + col] = f2bf(val);
      }
    }
  }
}

// ---------------- causal flash attention (swapped-QK^T, in-register P) ----------------
// grid: (S/128, B*H). 4 waves x 32 q-rows. KV tiles of 64, double-buffered.
// QK^T computed as mfma(K_rows_as_A, Q_as_B) -> S^T: lane owns one q (col), kv on rows.
// kv-rows fed in permuted order rho(nt,i)=32*(nt>>1)+8*(i>>2)+4*(nt&1)+(i&3) so that
// after softmax each lane's P values are EXACTLY the PV B-fragment (16 cvt_pk, no LDS).
// Q pre-scaled by log2(e)/sqrt(64); softmax in exp2 domain.
__global__ __launch_bounds__(256, 2)
void attn_kernel(const short* __restrict__ Q, const short* __restrict__ K,
                 const short* __restrict__ VT, const int* __restrict__ maskp,
                 short* __restrict__ O){
  __shared__ short Ks[2][64 * 64];
  __shared__ short Vs[2][64 * 64];     // V^T tile: rows = d, cols = kv
  const int t = threadIdx.x, w = t >> 6, l = t & 63;
  const int g = l >> 4, q16 = l & 15;
  const int bh = blockIdx.y, b = bh >> 4, h = bh & 15;
  const int qx = (blockIdx.y & 16) ? ((int)gridDim.x - 1 - (int)blockIdx.x) : (int)blockIdx.x;
  const int q0 = qx * 128;
  const int qw = q0 + w * 32;

  v8s qf[2][2];   // B-fragments of Q^T (same data layout as A-frag of Q)
  #pragma unroll
  for (int mi = 0; mi < 2; ++mi)
    #pragma unroll
    for (int kc = 0; kc < 2; ++kc)
      qf[mi][kc] = *reinterpret_cast<const v8s*>(
          &Q[(size_t)(b * S + qw + mi * 16 + q16) * D + h * 64 + kc * 32 + g * 8]);

  v4f accOT[2][4] = {};                // O^T accumulators: col=q(lane), row=d
  float mrow[2] = {-1e30f, -1e30f};
  float lrow[2] = {0.f, 0.f};

  auto stage = [&](int kt, int buf){
    const int kv0 = kt * 64;
    #pragma unroll
    for (int j = 0; j < 2; ++j){
      const int cix = j * 256 + t;
      const int row = cix >> 3;
      const int c   = (cix & 7) ^ swz(row);
      GLDS(K  + (size_t)(b * S + kv0 + row) * D + h * 64 + c * 8, &Ks[buf][cix * 8]);
      GLDS(VT + (size_t)(h * 64 + row) * M + b * S + kv0 + c * 8, &Vs[buf][cix * 8]);
    }
  };

  const int nkt = 2 * qx + 2;
  stage(0, 0);
  for (int kt = 0; kt < nkt; ++kt){
    const int cur = kt & 1;
    const int kv0 = kt * 64;
    __syncthreads();
    if (kt + 1 < nkt) stage(kt + 1, cur ^ 1);
    if (kv0 > qw + 31) continue;       // tile fully causal-masked for this wave

    // padding mask quads: lane needs kv = kv0 + 32*(nt>>1) + 8g + 4*(nt&1) + r
    v4i mq[4];
    #pragma unroll
    for (int nt = 0; nt < 4; ++nt)
      mq[nt] = *reinterpret_cast<const v4i*>(
          &maskp[b * S + kv0 + 32 * (nt >> 1) + 8 * g + 4 * (nt & 1)]);

    // QK^T (transposed scores) with rho-permuted kv rows
    v4f sc[2][4] = {};
    #pragma unroll
    for (int nt = 0; nt < 4; ++nt){
      const int R = 32 * (nt >> 1) + 8 * (q16 >> 2) + 4 * (nt & 1) + (l & 3);
      #pragma unroll
      for (int kc = 0; kc < 2; ++kc){
        v8s kf = *reinterpret_cast<const v8s*>(&Ks[cur][R * 64 + (((kc * 4 + g) ^ swz(R)) * 8)]);
        sc[0][nt] = __builtin_amdgcn_mfma_f32_16x16x32_bf16(kf, qf[0][kc], sc[0][nt], 0, 0, 0);
        sc[1][nt] = __builtin_amdgcn_mfma_f32_16x16x32_bf16(kf, qf[1][kc], sc[1][nt], 0, 0, 0);
      }
    }

    // fused padding+causal mask -> p[mi][j], j = nt*4+r, kv = kv0+32*(nt>>1)+8g+4*(nt&1)+r
    int kvx[16];
    #pragma unroll
    for (int nt = 0; nt < 4; ++nt)
      #pragma unroll
      for (int r = 0; r < 4; ++r){
        const int kvg = kv0 + 32 * (nt >> 1) + 8 * g + 4 * (nt & 1) + r;
        kvx[nt * 4 + r] = (mq[nt][r] != 0) ? kvg : 0x7fffffff;
      }

    float p[2][16];
    #pragma unroll
    for (int mi = 0; mi < 2; ++mi){
      const int qg = qw + mi * 16 + q16;
      #pragma unroll
      for (int j = 0; j < 16; ++j)
        p[mi][j] = (kvx[j] > qg) ? -1e30f : sc[mi][j >> 2][j & 3];
    }

    // per-lane online softmax (exp2 domain); cross-group reduce over lanes l^16, l^32
    #pragma unroll
    for (int mi = 0; mi < 2; ++mi){
      float tm = p[mi][0];
      #pragma unroll
      for (int j = 1; j < 16; ++j) tm = fmaxf(tm, p[mi][j]);
      tm = fmaxf(tm, __shfl_xor(tm, 16));
      tm = fmaxf(tm, __shfl_xor(tm, 32));
      const float mnew = fmaxf(mrow[mi], tm);
      const float resc = EXP2(mrow[mi] - mnew);
      float ps = 0.f;
      #pragma unroll
      for (int j = 0; j < 16; ++j){
        p[mi][j] = EXP2(p[mi][j] - mnew);
        ps += p[mi][j];
      }
      ps += __shfl_xor(ps, 16);
      ps += __shfl_xor(ps, 32);
      lrow[mi] = lrow[mi] * resc + ps;
      mrow[mi] = mnew;
      #pragma unroll
      for (int dt = 0; dt < 4; ++dt) accOT[mi][dt] *= resc;
    }

    // pack P into PV B-fragments: pb[mi][kc] word s pairs (nt=2kc+(s>>1), r=2(s&1), +1)
    int pb[2][2][4];
    #pragma unroll
    for (int mi = 0; mi < 2; ++mi)
      #pragma unroll
      for (int kc = 0; kc < 2; ++kc)
        #pragma unroll
        for (int s = 0; s < 4; ++s){
          const int base = (2 * kc + (s >> 1)) * 4 + (s & 1) * 2;
          pb[mi][kc][s] = cvtpk(p[mi][base], p[mi][base + 1]);
        }

    // PV: O^T[d][q] += V^T[d][kv] x P^T[kv][q]
    #pragma unroll
    for (int kc = 0; kc < 2; ++kc){
      v8s pbv[2];
      #pragma unroll
      for (int mi = 0; mi < 2; ++mi){
        v4i tmp = {pb[mi][kc][0], pb[mi][kc][1], pb[mi][kc][2], pb[mi][kc][3]};
        pbv[mi] = __builtin_bit_cast(v8s, tmp);
      }
      #pragma unroll
      for (int dt = 0; dt < 4; ++dt){
        const int R = dt * 16 + q16;
        v8s vf = *reinterpret_cast<const v8s*>(&Vs[cur][R * 64 + (((kc * 4 + g) ^ swz(R)) * 8)]);
        accOT[0][dt] = __builtin_amdgcn_mfma_f32_16x16x32_bf16(vf, pbv[0], accOT[0][dt], 0, 0, 0);
        accOT[1][dt] = __builtin_amdgcn_mfma_f32_16x16x32_bf16(vf, pbv[1], accOT[1][dt], 0, 0, 0);
      }
    }
  }

  // epilogue: O[q][d] = accOT^T / l ; 4 consecutive d per (mi,dt) -> 8B stores
  #pragma unroll
  for (int mi = 0; mi < 2; ++mi){
    const float inv = 1.0f / lrow[mi];
    #pragma unroll
    for (int dt = 0; dt < 4; ++dt){
      v4s o4;
      #pragma unroll
      for (int r = 0; r < 4; ++r) o4[r] = f2bf(accOT[mi][dt][r] * inv);
      *reinterpret_cast<v4s*>(
          &O[(size_t)(b * S + qw + mi * 16 + q16) * D + h * 64 + dt * 16 + g * 4]) = o4;
    }
  }
}

extern "C" void kernel_launch(void* const* d_in, const int* in_sizes, int n_in,
                              void* d_out, int out_size, void* d_ws, size_t ws_size,
                              hipStream_t stream){
  const float* x   = (const float*)d_in[0];
  const float* tg  = (const float*)d_in[1];
  const int*   msk = (const int*)d_in[2];
  const float* Wq  = (const float*)d_in[3];
  const float* bq  = (const float*)d_in[4];
  const float* Wk  = (const float*)d_in[5];
  const float* bk  = (const float*)d_in[6];
  const float* Wv  = (const float*)d_in[7];
  const float* bv  = (const float*)d_in[8];
  const float* Wo  = (const float*)d_in[9];
  const float* bo  = (const float*)d_in[10];
  const float* Wt  = (const float*)d_in[11];
  const float* bt  = (const float*)d_in[12];

  char* ws = (char*)d_ws;
  const size_t MB = 1u << 20;
  short* xb  = (short*)(ws);             // 8 MB
  short* xtb = (short*)(ws + 8 * MB);    // 8 MB
  short* Wqb = (short*)(ws + 16 * MB);   // 2 MB each
  short* Wkb = (short*)(ws + 18 * MB);
  short* Wvb = (short*)(ws + 20 * MB);
  short* Wob = (short*)(ws + 22 * MB);
  short* Qb  = (short*)(ws + 24 * MB);   // 8 MB
  short* Kb  = (short*)(ws + 32 * MB);
  short* VTb = (short*)(ws + 40 * MB);   // V^T [1024][4096]
  short* Ab  = (short*)(ws + 48 * MB);   // 8 MB -> 56 MB total

  prep_kernel<<<4096, 256, 0, stream>>>(x, tg, Wt, bt, xb, xtb);
  WPtrs wp; wp.s[0] = Wq; wp.s[1] = Wk; wp.s[2] = Wv; wp.s[3] = Wo;
  wp.d[0] = Wqb; wp.d[1] = Wkb; wp.d[2] = Wvb; wp.d[3] = Wob;
  wconv4_kernel<<<dim3(1024, 4), 256, 0, stream>>>(wp);

  dim3 ggrid(M / 128, D / 128);
  const float qalpha = 0.125f * 1.4426950408889634f;   // 1/sqrt(64) * log2(e)
  gemm_bt<false, false><<<ggrid, 256, 0, stream>>>(xtb, Wqb, bq, qalpha, Qb, D);
  gemm_bt<false, false><<<ggrid, 256, 0, stream>>>(xtb, Wkb, bk, 1.0f, Kb, D);
  // V^T: rows = feature n, cols = token m  (swapped operands, bias per row)
  gemm_bt<false, true><<<dim3(D / 128, M / 128), 256, 0, stream>>>(Wvb, xb, bv, 1.0f, VTb, M);

  attn_kernel<<<dim3(S / 128, Bb * H), 256, 0, stream>>>(Qb, Kb, VTb, msk, Ab);

  gemm_bt<true, false><<<ggrid, 256, 0, stream>>>(Ab, Wob, bo, 1.0f, d_out, D);
}

// Round 4
// 140.332 us; speedup vs baseline: 2.2078x; 1.1837x over previous
//
#include <hip/hip_runtime.h>

typedef short v8s __attribute__((ext_vector_type(8)));
typedef short v4s __attribute__((ext_vector_type(4)));
typedef float v4f __attribute__((ext_vector_type(4)));
typedef int   v4i __attribute__((ext_vector_type(4)));

constexpr int Bb = 2, S = 2048, D = 1024, H = 16;
constexpr int M = Bb * S;   // 4096

#define DEV __device__ __forceinline__

DEV short f2bf(float f){
  unsigned u = __builtin_bit_cast(unsigned, f);
  u = (u + 0x7FFF + ((u >> 16) & 1)) >> 16;
  return (short)u;
}

DEV int swz(int r){ return (r ^ (r >> 2)) & 7; }

DEV int cvtpk(float lo, float hi){
  int r;
  asm("v_cvt_pk_bf16_f32 %0, %1, %2" : "=v"(r) : "v"(lo), "v"(hi));
  return r;
}

#define EXP2 exp2f

#define GLDS(gp, lp) __builtin_amdgcn_global_load_lds( \
    (const __attribute__((address_space(1))) void*)(gp), \
    (__attribute__((address_space(3))) void*)(lp), 16, 0, 0)

// ---------------- fused prep: x/xtb bf16 conversion + 4 weight conversions ----------------
struct PrepArgs {
  const float* x; const float* tg; const float* Wt; const float* bt;
  const float* Ws0; const float* Ws1; const float* Ws2; const float* Ws3;
  short* Wd0; short* Wd1; short* Wd2; short* Wd3;
  short* xb; short* xtb;
};
__global__ void prep_all(PrepArgs a){
  const int bx = blockIdx.x;
  if (bx < 4096){
    int i = bx * 256 + threadIdx.x;
    int row = i >> 8;
    int c4  = i & 255;
    float4 xv = reinterpret_cast<const float4*>(a.x)[i];
    float4 wv = reinterpret_cast<const float4*>(a.Wt)[c4];
    float4 bv = reinterpret_cast<const float4*>(a.bt)[c4];
    float g = a.tg[row];
    float xs[4] = {xv.x, xv.y, xv.z, xv.w};
    float ws[4] = {wv.x, wv.y, wv.z, wv.w};
    float bs[4] = {bv.x, bv.y, bv.z, bv.w};
    v4s p, q;
    #pragma unroll
    for (int e = 0; e < 4; ++e){
      p[e] = f2bf(xs[e]);
      q[e] = f2bf(xs[e] + g * ws[e] + bs[e]);
    }
    *reinterpret_cast<v4s*>(&a.xb[(size_t)i * 4])  = p;
    *reinterpret_cast<v4s*>(&a.xtb[(size_t)i * 4]) = q;
  } else {
    const int bi = bx - 4096;
    const int widx = bi >> 10;
    const float* src = widx == 0 ? a.Ws0 : widx == 1 ? a.Ws1 : widx == 2 ? a.Ws2 : a.Ws3;
    short* dst = widx == 0 ? a.Wd0 : widx == 1 ? a.Wd1 : widx == 2 ? a.Wd2 : a.Wd3;
    int i = (bi & 1023) * 256 + threadIdx.x;
    float4 v = reinterpret_cast<const float4*>(src)[i];
    v4s o; o[0] = f2bf(v.x); o[1] = f2bf(v.y); o[2] = f2bf(v.z); o[3] = f2bf(v.w);
    *reinterpret_cast<v4s*>(&dst[(size_t)i * 4]) = o;
  }
}

// ---------------- GEMM core: C[m,n] = (sum_k A[m,k]*Bw[n,k] + bias) * alpha ----------------
// MODE 0: bf16 out, bias[col]. MODE 1: bf16 out, bias[row]. MODE 2: f32 out, bias[col].
// BK=64, XOR-swizzled LDS, double-buffered staging, one barrier per K-step.
template<int MODE>
DEV void gemm_core(const short* __restrict__ A, const short* __restrict__ Bw,
                   const float* __restrict__ bias, float alpha, void* __restrict__ Cout,
                   int ldc, int m0, int n0){
  __shared__ short As[2][128 * 64];
  __shared__ short Bs[2][128 * 64];
  const int t = threadIdx.x;
  const int w = t >> 6, l = t & 63;
  const int wm = (w >> 1) * 64, wn = (w & 1) * 64;

  v4f acc[4][4] = {};

  auto stage = [&](int kt, int buf){
    const int k0 = kt * 64;
    #pragma unroll
    for (int j = 0; j < 4; ++j){
      const int cix = j * 256 + t;
      const int row = cix >> 3;
      const int c   = (cix & 7) ^ swz(row);
      GLDS(A  + (size_t)(m0 + row) * D + k0 + c * 8, &As[buf][cix * 8]);
      GLDS(Bw + (size_t)(n0 + row) * D + k0 + c * 8, &Bs[buf][cix * 8]);
    }
  };

  stage(0, 0);
  for (int kt = 0; kt < 16; ++kt){
    const int cur = kt & 1;
    __syncthreads();
    if (kt < 15) stage(kt + 1, cur ^ 1);
    #pragma unroll
    for (int kk = 0; kk < 2; ++kk){
      v8s af[4], bfr[4];
      #pragma unroll
      for (int mi = 0; mi < 4; ++mi){
        const int R = wm + mi * 16 + (l & 15);
        af[mi] = *reinterpret_cast<const v8s*>(&As[cur][R * 64 + (((kk * 4 + (l >> 4)) ^ swz(R)) * 8)]);
      }
      #pragma unroll
      for (int ni = 0; ni < 4; ++ni){
        const int R = wn + ni * 16 + (l & 15);
        bfr[ni] = *reinterpret_cast<const v8s*>(&Bs[cur][R * 64 + (((kk * 4 + (l >> 4)) ^ swz(R)) * 8)]);
      }
      #pragma unroll
      for (int mi = 0; mi < 4; ++mi)
        #pragma unroll
        for (int ni = 0; ni < 4; ++ni)
          acc[mi][ni] = __builtin_amdgcn_mfma_f32_16x16x32_bf16(af[mi], bfr[ni], acc[mi][ni], 0, 0, 0);
    }
  }

  #pragma unroll
  for (int mi = 0; mi < 4; ++mi){
    const int row = m0 + wm + mi * 16 + (l >> 4) * 4;
    #pragma unroll
    for (int ni = 0; ni < 4; ++ni){
      const int col = n0 + wn + ni * 16 + (l & 15);
      const float bcol = (MODE == 1) ? 0.f : bias[col];
      #pragma unroll
      for (int r = 0; r < 4; ++r){
        float bsel = (MODE == 1) ? bias[row + r] : bcol;
        float val = (acc[mi][ni][r] + bsel) * alpha;
        if (MODE == 2) reinterpret_cast<float*>(Cout)[(size_t)(row + r) * ldc + col] = val;
        else           reinterpret_cast<short*>(Cout)[(size_t)(row + r) * ldc + col] = f2bf(val);
      }
    }
  }
}

template<int MODE>
__global__ __launch_bounds__(256, 2)
void gemm_bt(const short* __restrict__ A, const short* __restrict__ Bw,
             const float* __restrict__ bias, float alpha, void* __restrict__ Cout, int ldc){
  gemm_core<MODE>(A, Bw, bias, alpha, Cout, ldc, blockIdx.x * 128, blockIdx.y * 128);
}

// fused Q+K projection: both read A=xtb; y<8 -> Q tile, y>=8 -> K tile
__global__ __launch_bounds__(256, 2)
void gemm_qk(const short* __restrict__ A, const short* __restrict__ Wq,
             const short* __restrict__ Wk, const float* __restrict__ bq,
             const float* __restrict__ bk, float qalpha,
             short* __restrict__ Qb, short* __restrict__ Kb){
  const bool isK = blockIdx.y >= 8;
  gemm_core<0>(A, isK ? Wk : Wq, isK ? bk : bq, isK ? 1.0f : qalpha,
               isK ? (void*)Kb : (void*)Qb, D, blockIdx.x * 128, (blockIdx.y & 7) * 128);
}

// ---------------- causal flash attention (swapped-QK^T, in-register P) ----------------
// grid: (S/128, B*H). 8 waves x 16 q-rows = 128 q-rows per block. KV tiles of 64, dbuf.
// QK^T computed as mfma(K, Q) -> S^T: lane owns one q-row, kv on MFMA rows.
// kv rows fed in permuted order rho(nt,i)=32*(nt>>1)+8*(i>>2)+4*(nt&1)+(i&3) so each
// lane's 16 P values are exactly the PV B-fragment (8 cvt_pk, no LDS round-trip).
// Q pre-scaled by log2(e)/sqrt(64); softmax in exp2 domain.
__global__ __launch_bounds__(512, 4)
void attn_kernel(const short* __restrict__ Q, const short* __restrict__ K,
                 const short* __restrict__ VT, const int* __restrict__ maskp,
                 short* __restrict__ O){
  __shared__ short Ks[2][64 * 64];
  __shared__ short Vs[2][64 * 64];     // V^T tile: rows = d, cols = kv
  const int t = threadIdx.x, w = t >> 6, l = t & 63;
  const int g = l >> 4, q16 = l & 15;
  const int bh = blockIdx.y, b = bh >> 4, h = bh & 15;
  const int qx = (blockIdx.y & 16) ? ((int)gridDim.x - 1 - (int)blockIdx.x) : (int)blockIdx.x;
  const int q0 = qx * 128;
  const int qw = q0 + w * 16;          // wave's 16 q-rows
  const int qg = qw + q16;             // this lane's q row

  v8s qf[2];
  #pragma unroll
  for (int kc = 0; kc < 2; ++kc)
    qf[kc] = *reinterpret_cast<const v8s*>(
        &Q[(size_t)(b * S + qg) * D + h * 64 + kc * 32 + g * 8]);

  v4f accOT[4] = {};                   // O^T: col=q(lane), rows=d
  float mrow = -1e30f, lrow = 0.f;

  auto stage = [&](int kt, int buf){
    const int kv0 = kt * 64;
    const int row = t >> 3;
    const int c   = (t & 7) ^ swz(row);
    GLDS(K  + (size_t)(b * S + kv0 + row) * D + h * 64 + c * 8, &Ks[buf][t * 8]);
    GLDS(VT + (size_t)(h * 64 + row) * M + b * S + kv0 + c * 8, &Vs[buf][t * 8]);
  };

  const int nkt = 2 * qx + 2;
  stage(0, 0);
  for (int kt = 0; kt < nkt; ++kt){
    const int cur = kt & 1;
    const int kv0 = kt * 64;
    __syncthreads();
    if (kt + 1 < nkt) stage(kt + 1, cur ^ 1);
    if (kv0 > qw + 15) continue;       // tile fully above causal diagonal for this wave

    // padding-mask quads (issued early; latency hides under QK MFMAs)
    v4i mq[4];
    #pragma unroll
    for (int nt = 0; nt < 4; ++nt)
      mq[nt] = *reinterpret_cast<const v4i*>(
          &maskp[b * S + kv0 + 32 * (nt >> 1) + 8 * g + 4 * (nt & 1)]);

    // QK^T (transposed scores) with rho-permuted kv rows
    v4f sc[4] = {};
    #pragma unroll
    for (int nt = 0; nt < 4; ++nt){
      const int R = 32 * (nt >> 1) + 8 * (q16 >> 2) + 4 * (nt & 1) + (l & 3);
      #pragma unroll
      for (int kc = 0; kc < 2; ++kc){
        v8s kf = *reinterpret_cast<const v8s*>(&Ks[cur][R * 64 + (((kc * 4 + g) ^ swz(R)) * 8)]);
        sc[nt] = __builtin_amdgcn_mfma_f32_16x16x32_bf16(kf, qf[kc], sc[nt], 0, 0, 0);
      }
    }

    // mask: interior+all-valid tiles skip everything
    bool lv = true;
    #pragma unroll
    for (int nt = 0; nt < 4; ++nt)
      #pragma unroll
      for (int r = 0; r < 4; ++r) lv = lv && (mq[nt][r] != 0);
    const bool allv = __all(lv);

    float p[16];
    if (allv && (kv0 + 63 <= qw)) {
      #pragma unroll
      for (int j = 0; j < 16; ++j) p[j] = sc[j >> 2][j & 3];
    } else if (allv) {
      #pragma unroll
      for (int nt = 0; nt < 4; ++nt)
        #pragma unroll
        for (int r = 0; r < 4; ++r){
          const int kvg = kv0 + 32 * (nt >> 1) + 8 * g + 4 * (nt & 1) + r;
          p[nt * 4 + r] = (kvg > qg) ? -1e30f : sc[nt][r];
        }
    } else {
      #pragma unroll
      for (int nt = 0; nt < 4; ++nt)
        #pragma unroll
        for (int r = 0; r < 4; ++r){
          const int kvg = kv0 + 32 * (nt >> 1) + 8 * g + 4 * (nt & 1) + r;
          const int kvx = (mq[nt][r] != 0) ? kvg : 0x7fffffff;
          p[nt * 4 + r] = (kvx > qg) ? -1e30f : sc[nt][r];
        }
    }

    // per-lane online softmax (exp2 domain); cross-lane reduce over l^16, l^32
    float tm = fmaxf(fmaxf(fmaxf(p[0], p[1]), fmaxf(p[2], p[3])),
                     fmaxf(fmaxf(p[4], p[5]), fmaxf(p[6], p[7])));
    tm = fmaxf(tm, fmaxf(fmaxf(fmaxf(p[8], p[9]), fmaxf(p[10], p[11])),
                         fmaxf(fmaxf(p[12], p[13]), fmaxf(p[14], p[15]))));
    tm = fmaxf(tm, __shfl_xor(tm, 16));
    tm = fmaxf(tm, __shfl_xor(tm, 32));
    const float mnew = fmaxf(mrow, tm);
    if (!__all(mnew == mrow)){         // T13: skip rescale when no lane's max moved
      const float resc = EXP2(mrow - mnew);
      lrow *= resc;
      #pragma unroll
      for (int dt = 0; dt < 4; ++dt) accOT[dt] *= resc;
      mrow = mnew;
    }
    float ps = 0.f;
    #pragma unroll
    for (int j = 0; j < 16; ++j){
      p[j] = EXP2(p[j] - mrow);
      ps += p[j];
    }
    ps += __shfl_xor(ps, 16);
    ps += __shfl_xor(ps, 32);
    lrow += ps;

    // pack P into PV B-fragments
    int pb[2][4];
    #pragma unroll
    for (int kc = 0; kc < 2; ++kc)
      #pragma unroll
      for (int s = 0; s < 4; ++s){
        const int base = (2 * kc + (s >> 1)) * 4 + (s & 1) * 2;
        pb[kc][s] = cvtpk(p[base], p[base + 1]);
      }

    // PV: O^T[d][q] += V^T[d][kv] x P^T[kv][q]
    #pragma unroll
    for (int kc = 0; kc < 2; ++kc){
      v4i tmp = {pb[kc][0], pb[kc][1], pb[kc][2], pb[kc][3]};
      v8s pbv = __builtin_bit_cast(v8s, tmp);
      #pragma unroll
      for (int dt = 0; dt < 4; ++dt){
        const int R = dt * 16 + q16;
        v8s vf = *reinterpret_cast<const v8s*>(&Vs[cur][R * 64 + (((kc * 4 + g) ^ swz(R)) * 8)]);
        accOT[dt] = __builtin_amdgcn_mfma_f32_16x16x32_bf16(vf, pbv, accOT[dt], 0, 0, 0);
      }
    }
  }

  // epilogue: O[q][d] = accOT^T / l
  const float inv = 1.0f / lrow;
  #pragma unroll
  for (int dt = 0; dt < 4; ++dt){
    v4s o4;
    #pragma unroll
    for (int r = 0; r < 4; ++r) o4[r] = f2bf(accOT[dt][r] * inv);
    *reinterpret_cast<v4s*>(
        &O[(size_t)(b * S + qg) * D + h * 64 + dt * 16 + g * 4]) = o4;
  }
}

extern "C" void kernel_launch(void* const* d_in, const int* in_sizes, int n_in,
                              void* d_out, int out_size, void* d_ws, size_t ws_size,
                              hipStream_t stream){
  const float* x   = (const float*)d_in[0];
  const float* tg  = (const float*)d_in[1];
  const int*   msk = (const int*)d_in[2];
  const float* Wq  = (const float*)d_in[3];
  const float* bq  = (const float*)d_in[4];
  const float* Wk  = (const float*)d_in[5];
  const float* bk  = (const float*)d_in[6];
  const float* Wv  = (const float*)d_in[7];
  const float* bv  = (const float*)d_in[8];
  const float* Wo  = (const float*)d_in[9];
  const float* bo  = (const float*)d_in[10];
  const float* Wt  = (const float*)d_in[11];
  const float* bt  = (const float*)d_in[12];

  char* ws = (char*)d_ws;
  const size_t MB = 1u << 20;
  short* xb  = (short*)(ws);             // 8 MB
  short* xtb = (short*)(ws + 8 * MB);    // 8 MB
  short* Wqb = (short*)(ws + 16 * MB);   // 2 MB each
  short* Wkb = (short*)(ws + 18 * MB);
  short* Wvb = (short*)(ws + 20 * MB);
  short* Wob = (short*)(ws + 22 * MB);
  short* Qb  = (short*)(ws + 24 * MB);   // 8 MB
  short* Kb  = (short*)(ws + 32 * MB);
  short* VTb = (short*)(ws + 40 * MB);   // V^T [1024][4096]
  short* Ab  = (short*)(ws + 48 * MB);   // 8 MB -> 56 MB total

  PrepArgs pa;
  pa.x = x; pa.tg = tg; pa.Wt = Wt; pa.bt = bt;
  pa.Ws0 = Wq; pa.Ws1 = Wk; pa.Ws2 = Wv; pa.Ws3 = Wo;
  pa.Wd0 = Wqb; pa.Wd1 = Wkb; pa.Wd2 = Wvb; pa.Wd3 = Wob;
  pa.xb = xb; pa.xtb = xtb;
  prep_all<<<8192, 256, 0, stream>>>(pa);

  const float qalpha = 0.125f * 1.4426950408889634f;   // 1/sqrt(64) * log2(e)
  gemm_qk<<<dim3(M / 128, 16), 256, 0, stream>>>(xtb, Wqb, Wkb, bq, bk, qalpha, Qb, Kb);
  // V^T: rows = feature n, cols = token m  (swapped operands, bias per row)
  gemm_bt<1><<<dim3(D / 128, M / 128), 256, 0, stream>>>(Wvb, xb, bv, 1.0f, VTb, M);

  attn_kernel<<<dim3(S / 128, Bb * H), 512, 0, stream>>>(Qb, Kb, VTb, msk, Ab);

  gemm_bt<2><<<dim3(M / 128, D / 128), 256, 0, stream>>>(Ab, Wob, bo, 1.0f, d_out, D);
}